// Round 10
// baseline (1063.636 us; speedup 1.0000x reference)
//
#include <hip/hip_runtime.h>
#include <hip/hip_fp16.h>

// RNN_16492674416646: h_t = tanh(x_t W_ih^T + b_ih + b_hh + h_{t-1} W_hh^T),
// out_t = h_t W_out^T + b_out. T=2048, B=128, IN=2, H=200, OUT=1, fp32.
//
// R22 = R19 structure (best: 1010 us) + R17 i8 numerics (verified absmax
// 0.0078125, identical to fp16). The CLEAN test of the LDS-pipe model:
// A-reads 91 -> 52 b128/step with occupancy (4 tile-waves/SIMD), epilogue
// leanness, drain placement, unroll all held at R19's values.
//   reads: KT=4 (K=64 i8 MFMA) -> 4 b128/wave; writes: 13 b16 (DPP pair).
//   MFMA: 8/wave (A rows 0/1 = hq/hr free; B in {Wq, Wr} costs 2x).
// Numerics (R17, verified): h = hq/127 + hr/32000; W = gam*Wq + del*Wr,
// del = gam/252, per-column gam = colmax/127. All 4 cross terms kept.
// C2L = 2*log2(e) folded into a1..a4/wx/bA -> tanh = 1 - 2/(exp2(pre)+1).
// Ring slot 640 B: hq[224]@0, hr[224]@320 (320 % 128 = 64 -> hq banks
// 0..15, hr 16..31 on A-reads: conflict-free; R17 measured 0).
// Structure (R19, verified): 13 tile-waves, aux w13/14 DPP-only drain
// (1 output/step, 2-stale), w15 flushes 64 outs/64 steps, x8 unroll
// (static slots), 1 barrier/step.

typedef int   i4v __attribute__((ext_vector_type(4)));
typedef float f4v __attribute__((ext_vector_type(4)));

static constexpr int T = 2048;
static constexpr int B = 128;
static constexpr int H = 200;
static constexpr int NTHR = 1024;  // 16 waves
static constexpr int NT  = 13;     // n-tiles of 16 (208 >= 200)
static constexpr int KT  = 4;      // k-tiles of 64 (256 padded)
static constexpr int RS  = 8;      // ring slots; T % RS == 0
static constexpr int SLOT = 640;   // bytes per slot
static constexpr int HROFF = 320;  // hr row offset within slot

static constexpr float HA  = 1.f / 127.f;    // h hi scale
static constexpr float HB  = 1.f / 32000.f;  // h lo scale (|hr| <= 126)
static constexpr float C2L = 2.8853900817779268f;  // 2*log2(e)

// VALU-only cross-lane add (DPP); CTRL is a compile-time literal.
template <int CTRL>
__device__ __forceinline__ float dpp_add(float v) {
    const int i = __builtin_bit_cast(int, v);
    const int p = __builtin_amdgcn_update_dpp(0, i, CTRL, 0xF, 0xF, false);
    return v + __builtin_bit_cast(float, p);
}

__global__ __attribute__((amdgpu_flat_work_group_size(NTHR, NTHR),
                          amdgpu_waves_per_eu(4, 4)))
void rnn_fused(const float* __restrict__ x,     // [T,B,2]
               const float* __restrict__ W_ih,  // [H,2]
               const float* __restrict__ W_hh,  // [H,H]
               const float* __restrict__ b_ih,  // [H]
               const float* __restrict__ b_hh,  // [H]
               const float* __restrict__ W_out, // [1,H]
               const float* __restrict__ b_out, // [1]
               float* __restrict__ out)         // [T,B]
{
    const int b    = blockIdx.x;
    const int tid  = threadIdx.x;
    const int w    = tid >> 6;       // wave id 0..15
    const int lane = tid & 63;
    const int m    = lane & 15;      // A-row sel / B-col / D-col
    const int q    = lane >> 4;      // k-quad (16 consecutive k per lane)

    const bool hasT = (w < NT);      // 13 tile waves; 13/14 drain; 15 flush
    const int  nA   = 16 * w + m;
    const bool colv = hasT && (nA < H);

    __shared__ __align__(16) char  rbase[RS * SLOT];  // 5 KiB ring
    __shared__ __align__(16) float xs[2 * T];         // 16 KiB
    __shared__ __align__(16) float obuf[128];         // out staging

    for (int i = tid; i < RS * SLOT; i += NTHR) rbase[i] = 0;
    for (int idx = tid; idx < T; idx += NTHR) {
        const float2 v = *(const float2*)(x + (size_t)idx * (B * 2) + 2 * b);
        xs[2 * idx] = v.x; xs[2 * idx + 1] = v.y;
    }

    // --- per-column W scale: gam = colmax/127 (shared across same m) ---
    float cm = 0.f;
    if (colv) {
#pragma unroll
        for (int kt = 0; kt < KT; ++kt)
#pragma unroll
            for (int j = 0; j < 16; ++j) {
                const int ks = 64 * kt + 16 * q + j;
                if (ks < H) cm = fmaxf(cm, fabsf(W_hh[nA * H + ks]));
            }
    }
    cm = fmaxf(cm, __shfl_xor(cm, 16, 64));
    cm = fmaxf(cm, __shfl_xor(cm, 32, 64));
    const float gam = cm * (1.f / 127.f);
    const float del = gam * (1.f / 252.f);          // |Wr| <= 126, no clamp
    const float ivg = (cm > 0.f) ? (127.f / cm) : 0.f;
    const float ivd = (cm > 0.f) ? (32004.f / cm) : 0.f;   // 1/del

    // --- loop-invariant B-fragments: Wq, Wr (i8, 16 k per lane) ---
    i4v BQ[KT], BR[KT];
#pragma unroll
    for (int kt = 0; kt < KT; ++kt) {
        i4v vq = {0, 0, 0, 0}, vr = {0, 0, 0, 0};
        if (colv) {
#pragma unroll
            for (int j = 0; j < 16; ++j) {
                const int ks = 64 * kt + 16 * q + j;
                const float Wv = (ks < H) ? W_hh[nA * H + ks] : 0.f;
                const float fq = rintf(Wv * ivg);
                const float fr = rintf(fmaf(-fq, gam, Wv) * ivd);
                vq[j >> 2] |= (((int)fq) & 0xFF) << (8 * (j & 3));
                vr[j >> 2] |= (((int)fr) & 0xFF) << (8 * (j & 3));
            }
        }
        BQ[kt] = vq; BR[kt] = vr;
    }

    // --- epilogue constants (q==0 lanes own col nA), C2L folded ---
    const float a1 = C2L * gam * HA, a2 = C2L * del * HA;   // * QQ, * QR
    const float a3 = C2L * gam * HB, a4 = C2L * del * HB;   // * RQ, * RR
    const float wxA0 = colv ? (C2L * W_ih[nA * 2])     : 0.f;
    const float wxA1 = colv ? (C2L * W_ih[nA * 2 + 1]) : 0.f;
    const float bA   = colv ? (C2L * (b_ih[nA] + b_hh[nA])) : 0.f;

    // --- head constants (drain path): lane covers cols 4*lane..+3 ---
    const int c4 = 4 * lane;
    f4v wo = {0.f, 0.f, 0.f, 0.f};
    if (c4 + 3 < H) wo = *(const f4v*)(W_out + c4);   // pads: wo = 0
    const float bo = b_out[0];

    __syncthreads();

    float* const op = out + b;
    const char* const apb = rbase + ((m == 1) ? HROFF : 0) + 16 * q;

    // drain output tout (slot static): 2 b32 reads + DPP-only reduce.
    auto drain = [&](int slot, int tout) {
        float v = 0.f;
        if (lane < 56) {   // cols 0..223; pads are 0 and wo=0 there
            const char* sp = rbase + slot * SLOT;
            const int hq4 = *(const int*)(sp + c4);
            const int hr4 = *(const int*)(sp + HROFF + c4);
            float sq = 0.f, sr2 = 0.f;
#pragma unroll
            for (int j = 0; j < 4; ++j) {
                const float qj = (float)((signed char)((hq4 >> (8 * j)) & 0xFF));
                const float rj = (float)((signed char)((hr4 >> (8 * j)) & 0xFF));
                sq  = fmaf(qj, wo[j], sq);
                sr2 = fmaf(rj, wo[j], sr2);
            }
            v = fmaf(HA, sq, HB * sr2);
        }
        v = dpp_add<0xB1>(v);    // quad_perm(1,0,3,2)
        v = dpp_add<0x4E>(v);    // quad_perm(2,3,0,1)
        v = dpp_add<0x141>(v);   // row_half_mirror
        v = dpp_add<0x140>(v);   // row_mirror  -> each lane: its row16 sum
        const float r1 = __builtin_bit_cast(float,
            __builtin_amdgcn_readlane(__builtin_bit_cast(int, v), 16));
        const float r2 = __builtin_bit_cast(float,
            __builtin_amdgcn_readlane(__builtin_bit_cast(int, v), 32));
        const float r3 = __builtin_bit_cast(float,
            __builtin_amdgcn_readlane(__builtin_bit_cast(int, v), 48));
        if (lane == 0) obuf[tout & 127] = ((v + r1) + (r2 + r3)) + bo;
    };

    for (int t8 = 0; t8 < T / RS; ++t8) {
        f4v xv0 = {0.f, 0.f, 0.f, 0.f};
        f4v xv1 = {0.f, 0.f, 0.f, 0.f};
#pragma unroll
        for (int rp = 0; rp < RS; ++rp) {
            const int t  = 8 * t8 + rp;
            const int sr = (rp + RS - 1) & (RS - 1);   // static read slot

            if (hasT) {
                if (rp == 0) {          // x for steps rp=0..3
                    xv0 = *(const f4v*)(xs + 16 * t8);
                    xv1 = *(const f4v*)(xs + 16 * t8 + 4);
                } else if (rp == 4) {   // x for steps rp=4..7
                    xv0 = *(const f4v*)(xs + 16 * t8 + 8);
                    xv1 = *(const f4v*)(xs + 16 * t8 + 12);
                }
                const int r2i = rp & 3;  // static register picks
                const float x0 = (r2i == 0) ? xv0[0] : (r2i == 1) ? xv0[2]
                               : (r2i == 2) ? xv1[0] : xv1[2];
                const float x1 = (r2i == 0) ? xv0[1] : (r2i == 1) ? xv0[3]
                               : (r2i == 2) ? xv1[1] : xv1[3];
                const float xterm = fmaf(x0, wxA0, fmaf(x1, wxA1, bA));

                // A: row0 hq, row1 hr, rows 2..15 dup row0. 4 b128 reads.
                const char* ap = apb + sr * SLOT;
                const i4v A0 = *(const i4v*)(ap);
                const i4v A1 = *(const i4v*)(ap + 64);
                const i4v A2 = *(const i4v*)(ap + 128);
                const i4v A3 = *(const i4v*)(ap + 192);

                // 4 chains (Wq x2, Wr x2), dep depth 2
                const i4v z = {0, 0, 0, 0};
                i4v qa = __builtin_amdgcn_mfma_i32_16x16x64_i8(A0, BQ[0], z, 0, 0, 0);
                i4v ra = __builtin_amdgcn_mfma_i32_16x16x64_i8(A0, BR[0], z, 0, 0, 0);
                i4v qb = __builtin_amdgcn_mfma_i32_16x16x64_i8(A2, BQ[2], z, 0, 0, 0);
                i4v rb = __builtin_amdgcn_mfma_i32_16x16x64_i8(A2, BR[2], z, 0, 0, 0);
                qa = __builtin_amdgcn_mfma_i32_16x16x64_i8(A1, BQ[1], qa, 0, 0, 0);
                ra = __builtin_amdgcn_mfma_i32_16x16x64_i8(A1, BR[1], ra, 0, 0, 0);
                qb = __builtin_amdgcn_mfma_i32_16x16x64_i8(A3, BQ[3], qb, 0, 0, 0);
                rb = __builtin_amdgcn_mfma_i32_16x16x64_i8(A3, BR[3], rb, 0, 0, 0);

                if (q == 0 && nA < H) {
                    const float fQQ = (float)(qa[0] + qb[0]);
                    const float fRQ = (float)(qa[1] + qb[1]);
                    const float fQR = (float)(ra[0] + rb[0]);
                    const float fRR = (float)(ra[1] + rb[1]);
                    const float pre = fmaf(a1, fQQ, fmaf(a2, fQR,
                                      fmaf(a3, fRQ, fmaf(a4, fRR, xterm))));
                    const float e2  = __builtin_amdgcn_exp2f(pre);
                    const float th  = 1.f - 2.f / (e2 + 1.f);   // tanh

                    // quantize h -> (hq, hr); |hr| <= 126
                    const float fq = rintf(th * 127.f);
                    const float fr = rintf(fmaf(fq, -HA, th) * 32000.f);
                    const int iq = ((int)fq) & 0xFF;
                    const int ir = ((int)fr) & 0xFF;

                    // DPP byte-pair (R17, verified): even m write b16
                    // {hq_m,hq_m+1} @ hq+nA; odd m {hr_m-1,hr_m} @ hr+nA-1.
                    const int nq = __builtin_amdgcn_update_dpp(
                        0, iq, 0xB1, 0xF, 0xF, true);
                    const int nr = __builtin_amdgcn_update_dpp(
                        0, ir, 0xB1, 0xF, 0xF, true);
                    char* sb = rbase + rp * SLOT;
                    const bool ev = ((m & 1) == 0);
                    const unsigned short wdat = ev
                        ? (unsigned short)(iq | (nq << 8))
                        : (unsigned short)(nr | (ir << 8));
                    char* wadr = ev ? (sb + nA) : (sb + HROFF + nA - 1);
                    *(unsigned short*)wadr = wdat;
                }
            } else if (w == 13 + (rp & 1)) {
                // drain output t-2 (slot (rp+6)&7, static): written 2 steps
                // ago, rewritten at t+6 -> stable. w13: even t, w14: odd t.
                if (t8 > 0 || rp >= 2) drain((rp + 6) & (RS - 1), t - 2);
            } else if (w == 15) {
                // flush chunk cc = outputs [64cc, 64cc+64) once per 64
                // steps; last of chunk drained at step 64cc+65 <= t here.
                if (rp == 0 && (t8 & 7) == 2 && t8 >= 10) {
                    const int cc = (t8 - 10) >> 3;            // 0..30
                    const float val = obuf[((cc & 1) << 6) | lane];
                    op[(size_t)(64 * cc + lane) * B] = val;
                }
            }
            __syncthreads();
        }
    }

    // --- tail: outputs 2046,2047 undrained; then flush chunk 31 ---
    if (w == 13) drain(6, 2046);
    if (w == 14) drain(7, 2047);
    __syncthreads();
    if (w == 15) {
        const float val = obuf[64 | lane];   // outputs 1984..2047
        op[(size_t)(1984 + lane) * B] = val;
    }
}

extern "C" void kernel_launch(void* const* d_in, const int* in_sizes, int n_in,
                              void* d_out, int out_size, void* d_ws, size_t ws_size,
                              hipStream_t stream) {
    const float* x     = (const float*)d_in[0];
    const float* W_ih  = (const float*)d_in[1];
    const float* W_hh  = (const float*)d_in[2];
    const float* b_ih  = (const float*)d_in[3];
    const float* b_hh  = (const float*)d_in[4];
    const float* W_out = (const float*)d_in[5];
    const float* b_out = (const float*)d_in[6];
    float* out = (float*)d_out;

    rnn_fused<<<B, NTHR, 0, stream>>>(x, W_ih, W_hh, b_ih, b_hh, W_out, b_out, out);
}